// Round 9
// baseline (24147.362 us; speedup 1.0000x reference)
//
#include <hip/hip_runtime.h>

// 2-layer tanh RNN, B=64, S=2048, D=HID=512.
// Round 9: XCD-clustered flag-sync with MEASURED, deterministic placement and
// a uniform agent-scope fallback.
//  Phase 0: every block publishes xcc_id to xcdmap[bid] (agent scope), then a
//           one-time global counter barrier (r3-proven mechanism).
//  Phase 1: every block reads the full map and identically computes: per-XCD
//           counts -> top-4 XCDs (count desc, id asc) -> bg c hosted by the
//           first 16 blocks (bid order) on chosen XCD c, 4 tiles (waves) each.
//           If any chosen XCD has <16 blocks or the map is malformed, ALL
//           blocks uniformly fall back to the r7-proven agent-scope protocol
//           with tile = blockIdx (correct, ~15.5 ms).
//  Fast path: all h/flag ops are volatile accesses (L1-bypass; CDNA L1 is
//  write-through, so producer stores land in the XCD's L2 and consumer
//  volatile loads on the same XCD must see them). No multi-operand asm.
//  Protocol (r7-proven): producer stores tile from MFMA C/D layout, drains
//  vmcnt, stamps flag=t+1; consumers ballot-poll 64 flags. 4-deep h slots;
//  L0 back-pressures on stamp_1 >= t-3. Bounded polls -> visible failure,
//  never a hang.

#define SEQ 2048

typedef _Float16 half8 __attribute__((ext_vector_type(8)));
typedef float floatx4 __attribute__((ext_vector_type(4)));
typedef unsigned long long u64;

#define MFMA(a, b, c) __builtin_amdgcn_mfma_f32_16x16x32_f16((a), (b), (c), 0, 0, 0)

__device__ inline half8 cvt8(const float* p) {
    float4 f0 = ((const float4*)p)[0];
    float4 f1 = ((const float4*)p)[1];
    half8 h;
    h[0]=(_Float16)f0.x; h[1]=(_Float16)f0.y; h[2]=(_Float16)f0.z; h[3]=(_Float16)f0.w;
    h[4]=(_Float16)f1.x; h[5]=(_Float16)f1.y; h[6]=(_Float16)f1.z; h[7]=(_Float16)f1.w;
    return h;
}

__device__ inline int xcc_id(void) {
    int x;
    asm volatile("s_getreg_b32 %0, hwreg(HW_REG_XCC_ID)" : "=s"(x));
    return x & 7;
}

// ---- FAST helpers: volatile = L1-bypass; coherent at the XCD's L2 ----
__device__ inline int f_ldflag(const int* p) { return *(volatile const int*)p; }
__device__ inline void f_stflag(int* p, int v) { *(volatile int*)p = v; }
__device__ inline void f_sth2(_Float16* p, _Float16 v) { *(volatile _Float16*)p = v; }
__device__ inline void f_ldfrag(const _Float16* p, half8 a[16]) {
    #pragma unroll
    for (int u = 0; u < 16; ++u) a[u] = *(volatile const half8*)(p + u * 32);
}

// ---- AGENT helpers (r7-proven, L3 coherence point) ----
__device__ inline int a_ldflag(const int* p) {
    return __hip_atomic_load(p, __ATOMIC_RELAXED, __HIP_MEMORY_SCOPE_AGENT);
}
__device__ inline void a_stflag(int* p, int v) {
    __hip_atomic_store(p, v, __ATOMIC_RELAXED, __HIP_MEMORY_SCOPE_AGENT);
}
__device__ inline void a_sth2(_Float16* p, _Float16 v) {
    union { _Float16 f; unsigned short s; } c; c.f = v;
    __hip_atomic_store((unsigned short*)p, c.s, __ATOMIC_RELAXED,
                       __HIP_MEMORY_SCOPE_AGENT);
}
__device__ inline void a_ldfrag(const _Float16* p, half8 a[16]) {
    #pragma unroll
    for (int u = 0; u < 16; ++u) {
        union { u64 d[2]; half8 h; } x;
        x.d[0] = __hip_atomic_load((const u64*)(p + u * 32),
                                   __ATOMIC_RELAXED, __HIP_MEMORY_SCOPE_AGENT);
        x.d[1] = __hip_atomic_load((const u64*)(p + u * 32) + 1,
                                   __ATOMIC_RELAXED, __HIP_MEMORY_SCOPE_AGENT);
        a[u] = x.h;
    }
}

template <bool FAST>
__device__ void run_rnn(int L, int jg, int bg, int lane,
                        const int* __restrict__ src, const float* __restrict__ embed,
                        const float* __restrict__ W_ih, const float* __restrict__ W_hh,
                        const float* __restrict__ b_ih, const float* __restrict__ b_hh,
                        float* __restrict__ out, _Float16* hbase, int* flags)
{
    const int q   = lane >> 4;
    const int rr  = lane & 15;
    const int col = jg * 16 + rr;

    // persistent weights: 16 cols x K=1024, f16, 128 VGPRs
    half8 bw[32];
    {
        const float* Wi = W_ih + ((size_t)L * 512 + col) * 512;
        const float* Wh = W_hh + ((size_t)L * 512 + col) * 512;
        #pragma unroll
        for (int u = 0; u < 16; ++u) bw[u]      = cvt8(Wi + u * 32 + q * 8);
        #pragma unroll
        for (int u = 0; u < 16; ++u) bw[16 + u] = cvt8(Wh + u * 32 + q * 8);
    }
    const float bias = b_ih[L * 512 + col] + b_hh[L * 512 + col];

    _Float16* hbg = hbase + (size_t)bg * 65536;   // L0: 4 slots x 8192; L1 at +32768
    int* flg   = flags + bg * 1024;               // [L(2)][jg(32)] stamps
    int* stamp = flg + L * 32 + jg;

    half8 ax[16];                                 // L0: embed A-frags, prefetched
    if (L == 0) {
        const int erow = src[(bg * 16 + rr) * SEQ + 0];
        const float* eb = embed + (size_t)erow * 512 + q * 8;
        #pragma unroll
        for (int u = 0; u < 16; ++u) ax[u] = cvt8(eb + u * 32);
    }

    bool dead = false;
    for (int t = 0; t < SEQ && !dead; ++t) {
        floatx4 acc0 = {0.f,0.f,0.f,0.f}, acc1 = {0.f,0.f,0.f,0.f};

        if (L == 0) {
            #pragma unroll
            for (int u = 0; u < 16; ++u) {        // x-part off the critical chain
                if (u & 1) acc1 = MFMA(ax[u], bw[u], acc1);
                else       acc0 = MFMA(ax[u], bw[u], acc0);
            }
            const int tgt = (lane < 32) ? t : (t - 3);   // peers t-1 done; L1 WAR
            int it = 0;
            while (true) {
                int v = FAST ? f_ldflag(flg + lane) : a_ldflag(flg + lane);
                if (__ballot(v >= tgt) == ~0ull) break;
                if (++it > (1 << 22)) { dead = true; break; }
                __builtin_amdgcn_s_sleep(1);
            }
            if (dead) break;
            __atomic_signal_fence(__ATOMIC_SEQ_CST);
            if (t > 0) {
                const _Float16* hp = hbg + ((t - 1) & 3) * 8192 + rr * 512 + q * 8;
                half8 ah[16];
                if (FAST) f_ldfrag(hp, ah); else a_ldfrag(hp, ah);
                #pragma unroll
                for (int u = 0; u < 16; ++u) {
                    if (u & 1) acc1 = MFMA(ah[u], bw[16 + u], acc1);
                    else       acc0 = MFMA(ah[u], bw[16 + u], acc0);
                }
            }
        } else {
            const int tgt = (lane < 32) ? (t + 1) : t;   // h0_t ready; L1 peers t-1
            int it = 0;
            while (true) {
                int v = FAST ? f_ldflag(flg + lane) : a_ldflag(flg + lane);
                if (__ballot(v >= tgt) == ~0ull) break;
                if (++it > (1 << 22)) { dead = true; break; }
                __builtin_amdgcn_s_sleep(1);
            }
            if (dead) break;
            __atomic_signal_fence(__ATOMIC_SEQ_CST);
            {
                const _Float16* xp = hbg + (t & 3) * 8192 + rr * 512 + q * 8;
                half8 xa[16];
                if (FAST) f_ldfrag(xp, xa); else a_ldfrag(xp, xa);
                #pragma unroll
                for (int u = 0; u < 16; ++u) {
                    if (u & 1) acc1 = MFMA(xa[u], bw[u], acc1);
                    else       acc0 = MFMA(xa[u], bw[u], acc0);
                }
            }
            if (t > 0) {
                const _Float16* hp = hbg + 32768 + ((t - 1) & 3) * 8192
                                   + rr * 512 + q * 8;
                half8 ah[16];
                if (FAST) f_ldfrag(hp, ah); else a_ldfrag(hp, ah);
                #pragma unroll
                for (int u = 0; u < 16; ++u) {
                    if (u & 1) acc1 = MFMA(ah[u], bw[16 + u], acc1);
                    else       acc0 = MFMA(ah[u], bw[16 + u], acc0);
                }
            }
        }

        // finalize: bias + tanh; C/D layout row=q*4+r, col=rr
        float hv[4];
        #pragma unroll
        for (int r = 0; r < 4; ++r)
            hv[r] = tanhf(acc0[r] + acc1[r] + bias);

        if (t == SEQ - 1) {
            #pragma unroll
            for (int r = 0; r < 4; ++r)
                out[(size_t)L * 64 * 512 + (size_t)(bg * 16 + q * 4 + r) * 512 + col]
                    = hv[r];
        }

        // store tile, drain, stamp
        {
            _Float16* hw = hbg + (L ? 32768 : 0) + (t & 3) * 8192 + col;
            #pragma unroll
            for (int r = 0; r < 4; ++r) {
                if (FAST) f_sth2(hw + (q * 4 + r) * 512, (_Float16)hv[r]);
                else      a_sth2(hw + (q * 4 + r) * 512, (_Float16)hv[r]);
            }
        }
        __atomic_signal_fence(__ATOMIC_SEQ_CST);
        __builtin_amdgcn_s_waitcnt(0);          // h stores at the coherence point
        __atomic_signal_fence(__ATOMIC_SEQ_CST);
        if (lane == 0) {
            if (FAST) f_stflag(stamp, t + 1); else a_stflag(stamp, t + 1);
        }

        // prefetch next embed row (hides under next poll)
        if (L == 0 && t + 1 < SEQ) {
            const int erow = src[(bg * 16 + rr) * SEQ + (t + 1)];
            const float* eb = embed + (size_t)erow * 512 + q * 8;
            #pragma unroll
            for (int u = 0; u < 16; ++u) ax[u] = cvt8(eb + u * 32);
        }
    }
}

__global__ __launch_bounds__(256, 1)
void rnn_v9(const int* __restrict__ src, const float* __restrict__ embed,
            const float* __restrict__ W_ih, const float* __restrict__ W_hh,
            const float* __restrict__ b_ih, const float* __restrict__ b_hh,
            float* __restrict__ out, _Float16* hbase, int* flags,
            int* xcdmap, int* barcnt)
{
    __shared__ int smap[256];
    __shared__ int s_top[4];
    __shared__ int s_ok;

    const int tid = threadIdx.x;
    const int bid = blockIdx.x;
    const int xcd = xcc_id();

    // ---- phase 0: publish placement, one-time global barrier ----
    if (tid == 0) {
        __hip_atomic_store(&xcdmap[bid], xcd + 1, __ATOMIC_RELAXED,
                           __HIP_MEMORY_SCOPE_AGENT);
        __builtin_amdgcn_s_waitcnt(0);
        __hip_atomic_fetch_add(barcnt, 1, __ATOMIC_RELAXED,
                               __HIP_MEMORY_SCOPE_AGENT);
        int it = 0;
        while (__hip_atomic_load(barcnt, __ATOMIC_RELAXED,
                                 __HIP_MEMORY_SCOPE_AGENT) < 256) {
            if (++it > (1 << 22)) break;        // non-co-resident -> fallback path
            __builtin_amdgcn_s_sleep(2);
        }
    }
    __syncthreads();

    // ---- phase 1: identical deterministic assignment in every block ----
    smap[tid] = __hip_atomic_load(&xcdmap[tid], __ATOMIC_RELAXED,
                                  __HIP_MEMORY_SCOPE_AGENT) - 1;
    __syncthreads();
    if (tid == 0) {
        int cnt[8] = {0,0,0,0,0,0,0,0};
        bool bad = false;
        for (int i = 0; i < 256; ++i) {
            int x = smap[i];
            if (x < 0 || x > 7) { bad = true; break; }
            cnt[x]++;
        }
        int order[8] = {0,1,2,3,4,5,6,7};
        for (int a = 0; a < 4 && !bad; ++a) {       // top-4 by (count desc, id asc)
            int best = a;
            for (int b = a + 1; b < 8; ++b)
                if (cnt[order[b]] > cnt[order[best]]) best = b;
            int tmp = order[a]; order[a] = order[best]; order[best] = tmp;
            if (cnt[order[a]] < 16) bad = true;
            s_top[a] = order[a];
        }
        s_ok = bad ? 0 : 1;
    }
    __syncthreads();

    const bool fast = (s_ok == 1);
    if (fast) {
        int slotIdx = -1;
        #pragma unroll
        for (int a = 0; a < 4; ++a) if (s_top[a] == xcd) slotIdx = a;
        if (slotIdx < 0) return;
        int rank = 0;                               // my position among my XCD's blocks
        for (int i = 0; i < bid; ++i) if (smap[i] == xcd) rank++;
        if (rank >= 16) return;
        const int w    = tid >> 6;                  // all 4 waves active
        const int tile = rank * 4 + w;              // 0..63
        run_rnn<true>(tile >> 5, tile & 31, slotIdx, tid & 63,
                      src, embed, W_ih, W_hh, b_ih, b_hh, out, hbase, flags);
    } else {
        if (tid >= 64) return;                      // r7 shape: wave 0, tile = bid
        run_rnn<false>(bid >> 7, bid & 31, (bid >> 5) & 3, tid,
                       src, embed, W_ih, W_hh, b_ih, b_hh, out, hbase, flags);
    }
}

extern "C" void kernel_launch(void* const* d_in, const int* in_sizes, int n_in,
                              void* d_out, int out_size, void* d_ws, size_t ws_size,
                              hipStream_t stream) {
    const int*   src   = (const int*)  d_in[0];
    const float* embed = (const float*)d_in[1];
    const float* W_ih  = (const float*)d_in[2];
    const float* W_hh  = (const float*)d_in[3];
    const float* b_ih  = (const float*)d_in[4];
    const float* b_hh  = (const float*)d_in[5];
    float*     out    = (float*)d_out;
    int*       barcnt = (int*)d_ws;                         // [0,256)
    int*       xcdmap = (int*)d_ws + 64;                    // [256,1280)
    int*       flags  = (int*)((char*)d_ws + 4096);         // 4 bg x 4 KB
    _Float16*  hbase  = (_Float16*)((char*)d_ws + 65536);   // 4 bg x 128 KB

    // ws re-poisoned to 0xAA each timed launch: zero barrier/map/flags.
    // h slots need no init (t==0 skips all h reads).
    hipMemsetAsync(d_ws, 0, 20480, stream);

    rnn_v9<<<dim3(256), dim3(256), 0, stream>>>(
        src, embed, W_ih, W_hh, b_ih, b_hh, out, hbase, flags, xcdmap, barcnt);
}